// Round 10
// baseline (404.422 us; speedup 1.0000x reference)
//
#include <hip/hip_runtime.h>

// ---------------- problem constants ----------------
constexpr int D_   = 256;
constexpr int NH_  = 8;
constexpr int DH_  = 32;
constexpr int NL_  = 4;
constexpr int NP_  = 4;
constexpr int FF_  = 1024;
constexpr int B_   = 2;
constexpr int S_   = 16660;
constexpr int NR_  = B_ * S_;   // 33320 rows

typedef __attribute__((ext_vector_type(8))) short bf16x8;
typedef __attribute__((ext_vector_type(4))) float f32x4;

__device__ __forceinline__ ushort f2bf(float f) {
  unsigned u = __float_as_uint(f);
  return (ushort)((u + 0x7FFFu + ((u >> 16) & 1u)) >> 16);
}

// ---------------- prep: qb = bf16(src+pos), srcb = bf16(src) ----------------
__global__ __launch_bounds__(256)
void prep_kernel(const float* __restrict__ src, const float* __restrict__ pos,
                 ushort* __restrict__ qb, ushort* __restrict__ srcb, int n4) {
  int i = blockIdx.x * 256 + threadIdx.x;
  if (i >= n4) return;
  float4 s = ((const float4*)src)[i];
  float4 p = ((const float4*)pos)[i];
  ushort4 sb = {f2bf(s.x), f2bf(s.y), f2bf(s.z), f2bf(s.w)};
  ushort4 q  = {f2bf(s.x + p.x), f2bf(s.y + p.y), f2bf(s.z + p.z), f2bf(s.w + p.w)};
  ((ushort4*)srcb)[i] = sb;
  ((ushort4*)qb)[i]   = q;
}

// ---------------- weight convert + transpose: Wt[n][k] = bf16(W[k][n]) ----------------
// layout (ushort offsets): Val 0 | OA 65536 | Out 163840 | W1 229376 | W2 491520
__global__ __launch_bounds__(256)
void cvt_weights(const float* __restrict__ Woff, const float* __restrict__ Wattn,
                 const float* __restrict__ Wval, const float* __restrict__ Wout,
                 const float* __restrict__ W1,  const float* __restrict__ W2,
                 ushort* __restrict__ out) {
  const int wi = blockIdx.y;
  const int i = blockIdx.x * 256 + threadIdx.x;
  const float* src; int K, N; size_t off;
  switch (wi) {
    case 0: src = Wval;  K = 256;  N = 256;  off = 0;      break;
    case 1: src = Woff;  K = 256;  N = 256;  off = 65536;  break;
    case 2: src = Wattn; K = 256;  N = 128;  off = 131072; break;
    case 3: src = Wout;  K = 256;  N = 256;  off = 163840; break;
    case 4: src = W1;    K = 256;  N = 1024; off = 229376; break;
    default:src = W2;    K = 1024; N = 256;  off = 491520; break;
  }
  if (i >= K * N) return;
  int k = i / N, n = i - k * N;
  out[off + (size_t)n * K + k] = f2bf(src[i]);
}

// ---------------- B-in-LDS GEMM, K=256, NP col-panels per block --------------------
// 128 rows x (NP*128) cols per block. A-frags (2 slices) loaded ONCE, reused across
// panels. Per panel: stage 64KB (swizzled-src global_load_lds), barrier, MFMA,
// epilogue, barrier. MODE: 0 f32 | 1 bf16 | 2 bf16+relu | 3 split offs/attn.
template<int MODE, int NPAN>
__global__ __launch_bounds__(256, 2)
void gemm_blds(const ushort* __restrict__ A, const ushort* __restrict__ Wpan,
               const float* __restrict__ bias, const float* __restrict__ bias2,
               void* __restrict__ C, void* __restrict__ C2, int M, int Ns) {
  __shared__ ushort Bs[128 * 256];   // 64 KB
  const int tid = threadIdx.x;
  const int l = tid & 63, w = tid >> 6;
  const int l15 = l & 15, kg = l >> 4;
  const int cxor = l15 & 7;
  const int bx = blockIdx.x, by = blockIdx.y;

  const int r0 = bx * 128 + w * 16 + l15;
  const int r1 = r0 + 64;
  const int r0c = min(r0, M - 1), r1c = min(r1, M - 1);
  const ushort* a0p = A + (size_t)r0c * 256 + kg * 8;
  const ushort* a1p = A + (size_t)r1c * 256 + kg * 8;
  bf16x8 a0[8], a1[8];
#pragma unroll
  for (int kk = 0; kk < 8; ++kk) a0[kk] = *(const bf16x8*)(a0p + kk * 32);
#pragma unroll
  for (int kk = 0; kk < 8; ++kk) a1[kk] = *(const bf16x8*)(a1p + kk * 32);

  const int orow0 = bx * 128 + w * 16 + kg * 4;

#pragma unroll
  for (int pn = 0; pn < NPAN; ++pn) {
    const int pc = by * NPAN + pn;     // global 128-col panel index
    const ushort* wp = Wpan + (size_t)pc * 128 * 256;
#pragma unroll
    for (int rnd = 0; rnd < 16; ++rnd) {
      int gi = rnd * 256 + tid;
      int col = gi >> 5;
      int glog = (gi & 31) ^ (col & 7);
      __builtin_amdgcn_global_load_lds(
          (const __attribute__((address_space(1))) void*)(wp + (size_t)col * 256 + glog * 8),
          (__attribute__((address_space(3))) void*)(Bs + (size_t)(rnd * 256 + w * 64) * 8),
          16, 0, 0);
    }
    float bj[8];
#pragma unroll
    for (int ct = 0; ct < 8; ++ct) {
      int colg = pc * 128 + ct * 16 + l15;
      if (MODE == 3) bj[ct] = (colg < 256) ? bias[colg] : bias2[colg - 256];
      else           bj[ct] = bias[colg];
    }
    __syncthreads();

    f32x4 acc0[8], acc1[8];
#pragma unroll
    for (int ct = 0; ct < 8; ++ct) {
      acc0[ct] = (f32x4){0.f, 0.f, 0.f, 0.f};
      acc1[ct] = (f32x4){0.f, 0.f, 0.f, 0.f};
    }
#pragma unroll
    for (int ct = 0; ct < 8; ++ct) {
      const int cb = (ct * 16 + l15) * 256;
#pragma unroll
      for (int kk = 0; kk < 8; ++kk) {
        bf16x8 b = *(const bf16x8*)(Bs + cb + (((kk * 4 + kg) ^ cxor) * 8));
        acc0[ct] = __builtin_amdgcn_mfma_f32_16x16x32_bf16(a0[kk], b, acc0[ct], 0, 0, 0);
        acc1[ct] = __builtin_amdgcn_mfma_f32_16x16x32_bf16(a1[kk], b, acc1[ct], 0, 0, 0);
      }
    }

    // epilogue for this panel (global stores only; Bs untouched)
#pragma unroll
    for (int sl = 0; sl < 2; ++sl) {
      const int rowb = orow0 + sl * 64;
#pragma unroll
      for (int ct = 0; ct < 8; ++ct) {
        const int colg = pc * 128 + ct * 16 + l15;
#pragma unroll
        for (int r = 0; r < 4; ++r) {
          const int row = rowb + r;
          if (row >= M) continue;
          float v = (sl ? acc1[ct][r] : acc0[ct][r]) + bj[ct];
          if (MODE == 2) v = fmaxf(v, 0.f);
          if (MODE == 3) {
            if (colg < 256) ((float*)C )[(size_t)row * 256 + colg]       = v;
            else            ((float*)C2)[(size_t)row * 128 + (colg-256)] = v;
          } else if (MODE == 0) {
            ((float*)C)[(size_t)row * Ns + colg] = v;
          } else {
            ((ushort*)C)[(size_t)row * Ns + colg] = f2bf(v);
          }
        }
      }
    }
    __syncthreads();   // all waves done reading Bs before next panel staging
  }
}

// ---------------- fused GEMM + residual + LayerNorm ------------------------------
// C_row = LN(res_row + A_row @ W^T + bias). 64 rows/block, N=256 via 2 in-block
// panels, K = KCH*256 via K-chunks. Wave w: rows bx*64+w*16+{kg*4+r}. Lane holds
// 16 cols (2 panels x 8 ct at l15). LN reduce over l15 via shfl_xor 1,2,4,8.
template<int KCH, bool WB>
__global__ __launch_bounds__(256, 2)
void gemm_ln(const ushort* __restrict__ A, const ushort* __restrict__ Wpan,
             const float* __restrict__ bias, const float* __restrict__ res,
             const float* __restrict__ g, const float* __restrict__ be,
             float* __restrict__ outf, ushort* __restrict__ outb, int M) {
  constexpr int K = KCH * 256;
  __shared__ ushort Bs[128 * 256];   // 64 KB
  const int tid = threadIdx.x;
  const int l = tid & 63, w = tid >> 6;
  const int l15 = l & 15, kg = l >> 4;
  const int cxor = l15 & 7;
  const int bx = blockIdx.x;

  const int r0 = bx * 64 + w * 16 + l15;
  const int r0c = min(r0, M - 1);
  const ushort* ap = A + (size_t)r0c * K + kg * 8;

  f32x4 acc[2][8];
#pragma unroll
  for (int p = 0; p < 2; ++p)
#pragma unroll
    for (int ct = 0; ct < 8; ++ct) acc[p][ct] = (f32x4){0.f, 0.f, 0.f, 0.f};

  for (int kc = 0; kc < KCH; ++kc) {
    bf16x8 a[8];
#pragma unroll
    for (int kk = 0; kk < 8; ++kk) a[kk] = *(const bf16x8*)(ap + kc * 256 + kk * 32);
#pragma unroll
    for (int p = 0; p < 2; ++p) {
      const ushort* wp = Wpan + (size_t)(p * 128) * K;
#pragma unroll
      for (int rnd = 0; rnd < 16; ++rnd) {
        int gi = rnd * 256 + tid;
        int col = gi >> 5;
        int glog = (gi & 31) ^ (col & 7);
        __builtin_amdgcn_global_load_lds(
            (const __attribute__((address_space(1))) void*)
                (wp + (size_t)col * K + kc * 256 + glog * 8),
            (__attribute__((address_space(3))) void*)(Bs + (size_t)(rnd * 256 + w * 64) * 8),
            16, 0, 0);
      }
      __syncthreads();   // staging + a[] loads drained
#pragma unroll
      for (int ct = 0; ct < 8; ++ct) {
        const int cb = (ct * 16 + l15) * 256;
#pragma unroll
        for (int kk = 0; kk < 8; ++kk) {
          bf16x8 b = *(const bf16x8*)(Bs + cb + (((kk * 4 + kg) ^ cxor) * 8));
          acc[p][ct] = __builtin_amdgcn_mfma_f32_16x16x32_bf16(a[kk], b, acc[p][ct], 0, 0, 0);
        }
      }
      __syncthreads();   // Bs free for next stage
    }
  }

  // ---- LN epilogue ----
  float gj[2][8], bej[2][8], bj[2][8];
#pragma unroll
  for (int p = 0; p < 2; ++p)
#pragma unroll
    for (int ct = 0; ct < 8; ++ct) {
      int col = p * 128 + ct * 16 + l15;
      gj[p][ct]  = g[col];
      bej[p][ct] = be[col];
      bj[p][ct]  = bias[col];
    }
  const int rowb = bx * 64 + w * 16 + kg * 4;
#pragma unroll
  for (int r = 0; r < 4; ++r) {
    const int row = rowb + r;
    const bool ok = row < M;
    const int rc = min(row, M - 1);
    float v[2][8];
    float s = 0.f, s2 = 0.f;
#pragma unroll
    for (int p = 0; p < 2; ++p)
#pragma unroll
      for (int ct = 0; ct < 8; ++ct) {
        int col = p * 128 + ct * 16 + l15;
        float t = acc[p][ct][r] + bj[p][ct] + res[(size_t)rc * 256 + col];
        v[p][ct] = t; s += t; s2 += t * t;
      }
#pragma unroll
    for (int o = 1; o <= 8; o <<= 1) {
      s  += __shfl_xor(s, o, 64);
      s2 += __shfl_xor(s2, o, 64);
    }
    const float mean = s * (1.f / 256.f);
    const float var  = s2 * (1.f / 256.f) - mean * mean;
    const float rstd = rsqrtf(var + 1e-5f);
    if (ok) {
#pragma unroll
      for (int p = 0; p < 2; ++p)
#pragma unroll
        for (int ct = 0; ct < 8; ++ct) {
          int col = p * 128 + ct * 16 + l15;
          float o = (v[p][ct] - mean) * rstd * gj[p][ct] + bej[p][ct];
          outf[(size_t)row * 256 + col] = o;
          if (WB) outb[(size_t)row * 256 + col] = f2bf(o);
        }
    }
  }
}

// ---------------- MSDA sampling: descriptor split + wide (16 B) gathers -------------
__global__ __launch_bounds__(256)
void msda_kernel(const ushort* __restrict__ value, const float* __restrict__ offs,
                 const float* __restrict__ attn, const float* __restrict__ ref,
                 ushort* __restrict__ out) {
  __shared__ int4   descI[4 * 136];
  __shared__ float4 descW[4 * 136];
  const int t = threadIdx.x;
  // bijective XCD swizzle: nwg = 8330 = 8*1041 + 2 (m204 form)
  const int orig = blockIdx.x;
  const int xcd = orig & 7, ii = orig >> 3;
  const int wg = (xcd < 2 ? xcd * 1042 : 2 * 1042 + (xcd - 2) * 1041) + ii;
  const int n0 = wg * 4;

  const int Hs[4] = {112, 56, 28, 14};
  const int st[4] = {0, 12544, 15680, 16464};

  // ---- phase 1: 2 descriptors per thread ----
#pragma unroll
  for (int rep = 0; rep < 2; ++rep) {
    const int di = t + rep * 256;
    const int q = di >> 7, h = (di >> 4) & 7, lp = di & 15;
    const int lv = lp >> 2;
    const int n = n0 + q;

    float lg = attn[(size_t)n * 128 + h * 16 + lp];
    float mx = lg;
#pragma unroll
    for (int o = 8; o; o >>= 1) mx = fmaxf(mx, __shfl_xor(mx, o, 64));
    float e = __expf(lg - mx);
    float ssum = e;
#pragma unroll
    for (int o = 8; o; o >>= 1) ssum += __shfl_xor(ssum, o, 64);
    const float aw = e / ssum;

    const int Hl = Hs[lv], Wl = Hs[lv];
    const float fS = (float)Wl;
    const float refx = ref[((size_t)n * 4 + lv) * 2 + 0];
    const float refy = ref[((size_t)n * 4 + lv) * 2 + 1];
    const float ox = offs[(size_t)n * 256 + h * 32 + lp * 2 + 0];
    const float oy = offs[(size_t)n * 256 + h * 32 + lp * 2 + 1];
    float x = fmaf(refx, fS, ox) - 0.5f;
    float y = fmaf(refy, fS, oy) - 0.5f;
    float x0f = floorf(x), y0f = floorf(y);
    float dx = x - x0f, dy = y - y0f;
    int x0 = (int)x0f, y0 = (int)y0f;
    int x0c = min(max(x0, 0), Wl - 1), x1c = min(max(x0 + 1, 0), Wl - 1);
    int y0c = min(max(y0, 0), Hl - 1), y1c = min(max(y0 + 1, 0), Hl - 1);
    bool vx0 = (x0 >= 0) && (x0 < Wl), vx1 = (x0 + 1 >= 0) && (x0 + 1 < Wl);
    bool vy0 = (y0 >= 0) && (y0 < Hl), vy1 = (y0 + 1 >= 0) && (y0 + 1 < Hl);
    int4 I;
    I.x = st[lv] + y0c * Wl + x0c;
    I.y = st[lv] + y0c * Wl + x1c;
    I.z = st[lv] + y1c * Wl + x0c;
    I.w = st[lv] + y1c * Wl + x1c;
    float4 Wv;
    Wv.x = (1.f - dx) * (1.f - dy) * ((vx0 && vy0) ? aw : 0.f);
    Wv.y = dx * (1.f - dy)         * ((vx1 && vy0) ? aw : 0.f);
    Wv.z = (1.f - dx) * dy         * ((vx0 && vy1) ? aw : 0.f);
    Wv.w = dx * dy                 * ((vx1 && vy1) ? aw : 0.f);
    const int slot = q * 136 + h * 17 + lp;
    descI[slot] = I;
    descW[slot] = Wv;
  }
  __syncthreads();

  // ---- phase 2: lane = (pth, h, cq): 16 B of head h, even/odd points by pth ----
  const int q = t >> 6, lane = t & 63;
  const int pth = lane >> 5;
  const int h  = (lane >> 2) & 7;
  const int cq = lane & 3;
  const int n = n0 + q;
  const int b = n / S_;
  const ushort* base = value + (size_t)b * S_ * 256 + h * 32 + cq * 8;

  float a[8] = {0.f, 0.f, 0.f, 0.f, 0.f, 0.f, 0.f, 0.f};
#pragma unroll
  for (int pt2 = 0; pt2 < 8; ++pt2) {
    const int pt = pt2 * 2 + pth;
    const int slot = q * 136 + h * 17 + pt;
    int4 I = descI[slot];
    float4 Wv = descW[slot];
    int   Ia[4] = {I.x, I.y, I.z, I.w};
    float Wa[4] = {Wv.x, Wv.y, Wv.z, Wv.w};
#pragma unroll
    for (int cr = 0; cr < 4; ++cr) {
      uint4 u = *(const uint4*)(base + (size_t)Ia[cr] * 256);
      const float wgt = Wa[cr];
      a[0] = fmaf(wgt, __uint_as_float(u.x << 16),         a[0]);
      a[1] = fmaf(wgt, __uint_as_float(u.x & 0xffff0000u), a[1]);
      a[2] = fmaf(wgt, __uint_as_float(u.y << 16),         a[2]);
      a[3] = fmaf(wgt, __uint_as_float(u.y & 0xffff0000u), a[3]);
      a[4] = fmaf(wgt, __uint_as_float(u.z << 16),         a[4]);
      a[5] = fmaf(wgt, __uint_as_float(u.z & 0xffff0000u), a[5]);
      a[6] = fmaf(wgt, __uint_as_float(u.w << 16),         a[6]);
      a[7] = fmaf(wgt, __uint_as_float(u.w & 0xffff0000u), a[7]);
    }
  }
#pragma unroll
  for (int i = 0; i < 8; ++i) a[i] += __shfl_xor(a[i], 32, 64);
  if (pth == 0) {
    uint4 o;
    o.x = ((uint)f2bf(a[1]) << 16) | f2bf(a[0]);
    o.y = ((uint)f2bf(a[3]) << 16) | f2bf(a[2]);
    o.z = ((uint)f2bf(a[5]) << 16) | f2bf(a[4]);
    o.w = ((uint)f2bf(a[7]) << 16) | f2bf(a[6]);
    *(uint4*)(out + (size_t)n * 256 + h * 32 + cq * 8) = o;
  }
}

// ---------------- launch ----------------
extern "C" void kernel_launch(void* const* d_in, const int* in_sizes, int n_in,
                              void* d_out, int out_size, void* d_ws, size_t ws_size,
                              hipStream_t stream) {
  const float* src    = (const float*)d_in[0];
  const float* pos    = (const float*)d_in[1];
  const float* refpts = (const float*)d_in[2];
  const float* W_off  = (const float*)d_in[5];
  const float* b_off  = (const float*)d_in[6];
  const float* W_attn = (const float*)d_in[7];
  const float* b_attn = (const float*)d_in[8];
  const float* W_val  = (const float*)d_in[9];
  const float* b_val  = (const float*)d_in[10];
  const float* W_out  = (const float*)d_in[11];
  const float* b_out  = (const float*)d_in[12];
  const float* g1     = (const float*)d_in[13];
  const float* be1    = (const float*)d_in[14];
  const float* g2     = (const float*)d_in[15];
  const float* be2    = (const float*)d_in[16];
  const float* W1     = (const float*)d_in[17];
  const float* b1     = (const float*)d_in[18];
  const float* W2     = (const float*)d_in[19];
  const float* b2     = (const float*)d_in[20];
  float* out = (float*)d_out;

  const size_t NF = (size_t)NR_ * 256;
  char* p = (char*)d_ws;
  ushort* qb   = (ushort*)p; p += NF * 2;   // xb overlays qb
  ushort* srcb = (ushort*)p; p += NF * 2;   // msdab overlays srcb
  ushort* valb = (ushort*)p; p += NF * 2;   // hid overlays valb..attn (NF*8 bytes)
  float*  offs = (float*) p; p += NF * 4;
  float*  attn = (float*) p; p += NF * 2;   // [N,128] fp32
  float*  x    = (float*) p; p += NF * 4;
  ushort* Wt   = (ushort*)p; p += 753664 * 2;
  ushort* msdab = srcb;
  ushort* xb    = qb;
  ushort* hid   = valb;
  ushort* WtVal = Wt;
  ushort* WtOA  = Wt + 65536;    // [384,256]: off cols then attn cols
  ushort* WtOut = Wt + 163840;
  ushort* Wt1   = Wt + 229376;
  ushort* Wt2   = Wt + 491520;

  dim3 blk(256);
  const int n4 = NR_ * 64;
  const int gr  = (NR_ + 127) / 128;   // 261
  const int gr2 = (NR_ + 63) / 64;     // 521

  prep_kernel<<<(n4 + 255) / 256, blk, 0, stream>>>(src, pos, qb, srcb, n4);
  cvt_weights<<<dim3(1024, 6), blk, 0, stream>>>(W_off, W_attn, W_val, W_out, W1, W2, Wt);
  // value = src @ W_val + b_val (bf16 out)
  gemm_blds<1, 1><<<dim3(gr, 2), blk, 0, stream>>>(srcb, WtVal, b_val, nullptr,
                                                   valb, nullptr, NR_, 256);
  // offsets + attn logits, merged N=384 GEMM with split epilogue
  gemm_blds<3, 1><<<dim3(gr, 3), blk, 0, stream>>>(qb, WtOA, b_off, b_attn,
                                                   offs, attn, NR_, 0);
  // sampling
  msda_kernel<<<NR_ / 4, blk, 0, stream>>>(valb, offs, attn, refpts, msdab);
  // fused: x = LN(src + msdab @ W_out^T + b_out), + bf16 copy xb
  gemm_ln<1, true ><<<gr2, blk, 0, stream>>>(msdab, WtOut, b_out, src, g1, be1,
                                             x, xb, NR_);
  // FFN1: hid = relu(x @ W1 + b1), bf16 out — A loaded once, 4 panels per block
  gemm_blds<2, 4><<<dim3(gr, 2), blk, 0, stream>>>(xb, Wt1, b1, nullptr,
                                                   hid, nullptr, NR_, 1024);
  // fused: out = LN(x + hid @ W2^T + b2), K=1024
  gemm_ln<4, false><<<gr2, blk, 0, stream>>>(hid, Wt2, b2, x, g2, be2,
                                             out, nullptr, NR_);
}